// Round 13
// baseline (123.320 us; speedup 1.0000x reference)
//
#include <hip/hip_runtime.h>
#include <math.h>

#define H 1024
#define V 50257
#define NTILES 6283      // ceil(V / 8) tiles of 8 rows (2 rows per wave)
#define NBLK 512         // fused kernel blocks; all co-resident (4 blocks/CU cap)
#define NB_FINAL 64

typedef float f32x4 __attribute__((ext_vector_type(4)));

// nontemporal float4 load: weight streams are single-use, >> L2
__device__ __forceinline__ float4 ntload4(const float* p) {
    f32x4 v = __builtin_nontemporal_load((const f32x4*)p);
    return make_float4(v.x, v.y, v.z, v.w);
}

__device__ __forceinline__ float wave_reduce_sum(float v) {
#pragma unroll
    for (int off = 32; off >= 1; off >>= 1)
        v += __shfl_xor(v, off, 64);
    return v;
}

// online softmax merge: (m,s) <- merge((m,s),(mi,si))
__device__ __forceinline__ void sm_merge(float& m, float& s, float mi, float si) {
    if (mi > m) {
        s = s * expf(m - mi) + si;   // m==-inf, s==0 -> si
        m = mi;
    } else if (si > 0.f) {
        s += si * expf(mi - m);
    }
}

#define LOADT(W, BO, tile) do {                                               \
    const int _b = (tile) * 8 + wave * 2;                                     \
    _Pragma("unroll")                                                         \
    for (int _r = 0; _r < 2; ++_r) {                                          \
        const int _row = (_b + _r < V) ? (_b + _r) : (V - 1);                 \
        const float* _w = W_out + (size_t)_row * H;                           \
        _Pragma("unroll")                                                     \
        for (int _it = 0; _it < 4; ++_it)                                     \
            W[_r][_it] = ntload4(_w + (_it * 64 + lane) * 4);                 \
        BO[_r] = b_out[_row];                                                 \
    }                                                                         \
} while (0)

#define COMPUTET(W, BO, tile) do {                                            \
    const int _b = (tile) * 8 + wave * 2;                                     \
    float _acc[2];                                                            \
    _Pragma("unroll")                                                         \
    for (int _r = 0; _r < 2; ++_r) {                                          \
        _acc[_r] = W[_r][0].x * hreg[0].x + W[_r][0].y * hreg[0].y            \
                 + W[_r][0].z * hreg[0].z + W[_r][0].w * hreg[0].w            \
                 + W[_r][1].x * hreg[1].x + W[_r][1].y * hreg[1].y            \
                 + W[_r][1].z * hreg[1].z + W[_r][1].w * hreg[1].w            \
                 + W[_r][2].x * hreg[2].x + W[_r][2].y * hreg[2].y            \
                 + W[_r][2].z * hreg[2].z + W[_r][2].w * hreg[2].w            \
                 + W[_r][3].x * hreg[3].x + W[_r][3].y * hreg[3].y            \
                 + W[_r][3].z * hreg[3].z + W[_r][3].w * hreg[3].w;           \
    }                                                                         \
    _Pragma("unroll")                                                         \
    for (int _r = 0; _r < 2; ++_r) _acc[_r] = wave_reduce_sum(_acc[_r]);      \
    if (lane == 0) {                                                          \
        _Pragma("unroll")                                                     \
        for (int _r = 0; _r < 2; ++_r) {                                      \
            const int _row = _b + _r;                                         \
            if (_row < V) {                                                   \
                const float _lg = _acc[_r] + BO[_r];                          \
                logits[_row] = _lg;                                           \
                sm_merge(m, s, _lg, 1.f);                                     \
            }                                                                 \
        }                                                                     \
    }                                                                         \
} while (0)

// Fused GRU + logits. 512 blocks, all co-resident (__launch_bounds__(256,4)
// guarantees >=4 blocks/CU of resources; 512 <= 256 CUs * 4). Phase 1: each
// block computes 2 GRU hidden indices. One-way flag barrier (device-scope
// counter, release/acquire) replaces the kernel boundary; the first W_out
// tile is prefetched UNDER the spin. Phase 2: R11's double-buffered persistent
// logits pipeline, unchanged.
__global__ __launch_bounds__(256, 4) void decoder_main_kernel(
    const int* __restrict__ ids, const float* __restrict__ emb,
    const float* __restrict__ hidden,
    const float* __restrict__ W_ih, const float* __restrict__ W_hh,
    const float* __restrict__ b_ih, const float* __restrict__ b_hh,
    const float* __restrict__ W_out, const float* __restrict__ b_out,
    float* __restrict__ logits, float* __restrict__ out_hidden,
    float* __restrict__ hnew,
    float* __restrict__ pmax, float* __restrict__ psum,
    unsigned int* __restrict__ cnt)
{
    const int t256 = threadIdx.x;
    const int wave = t256 >> 6;
    const int lane = t256 & 63;
    const int bid  = blockIdx.x;

    __shared__ float red[4][12];
    __shared__ float wm[4], wsv[4];

    // ---------------- phase 1: GRU (j = 2*bid, 2*bid+1) ----------------
    {
        float pbi0 = 0.f, pbi1 = 0.f, pbi2 = 0.f;
        float pbh0 = 0.f, pbh1 = 0.f, pbh2 = 0.f, ph = 0.f;
        if (t256 < 2) {
            const int j = 2 * bid + t256;
            pbi0 = b_ih[j]; pbi1 = b_ih[H + j]; pbi2 = b_ih[2*H + j];
            pbh0 = b_hh[j]; pbh1 = b_hh[H + j]; pbh2 = b_hh[2*H + j];
            ph = hidden[j];
        }

        const int id = ids[0];
        float4 x4 = ((const float4*)(emb + (size_t)id * H))[t256];
        const float4 h4 = ((const float4*)hidden)[t256];

        float4 w[12];                    // [jj*6 + 2*g] = W_ih, [+1] = W_hh
#pragma unroll
        for (int jj = 0; jj < 2; ++jj) {
            const int j = 2 * bid + jj;
#pragma unroll
            for (int g = 0; g < 3; ++g) {
                w[jj*6 + 2*g]     = ntload4(W_ih + ((size_t)g * H + j) * H + 4 * t256);
                w[jj*6 + 2*g + 1] = ntload4(W_hh + ((size_t)g * H + j) * H + 4 * t256);
            }
        }

        x4.x = fmaxf(x4.x, 0.f); x4.y = fmaxf(x4.y, 0.f);
        x4.z = fmaxf(x4.z, 0.f); x4.w = fmaxf(x4.w, 0.f);

        float acc[12];
#pragma unroll
        for (int k = 0; k < 12; ++k) {
            const float4 v = w[k];
            const float4 u = (k & 1) ? h4 : x4;   // even: W_ih*relu(x), odd: W_hh*h
            acc[k] = v.x * u.x + v.y * u.y + v.z * u.z + v.w * u.w;
        }
#pragma unroll
        for (int k = 0; k < 12; ++k) acc[k] = wave_reduce_sum(acc[k]);

        if (lane == 0) {
#pragma unroll
            for (int k = 0; k < 12; ++k) red[wave][k] = acc[k];
        }
        __syncthreads();
        if (t256 < 2) {
            float tt[6];
#pragma unroll
            for (int k = 0; k < 6; ++k) {
                const int c = t256 * 6 + k;
                tt[k] = red[0][c] + red[1][c] + red[2][c] + red[3][c];
            }
            const int j = 2 * bid + t256;
            const float ir  = tt[0] + pbi0,  hr_ = tt[1] + pbh0;
            const float iz  = tt[2] + pbi1,  hz  = tt[3] + pbh1;
            const float in_ = tt[4] + pbi2,  hn  = tt[5] + pbh2;
            const float r = 1.f / (1.f + expf(-(ir + hr_)));
            const float z = 1.f / (1.f + expf(-(iz + hz)));
            const float n = tanhf(in_ + r * hn);
            const float o = (1.f - z) * n + z * ph;
            hnew[j] = o;
            out_hidden[j] = o;
        }
    }

    // ---------------- one-way flag barrier ----------------
    __builtin_amdgcn_fence(__ATOMIC_RELEASE, "agent");
    __syncthreads();                     // writers' stores+fence before publish
    if (t256 == 0)
        __hip_atomic_fetch_add(cnt, 1u, __ATOMIC_RELEASE, __HIP_MEMORY_SCOPE_AGENT);

    // prefetch first W_out tile while spinning (independent of hnew)
    float4 wA[2][4], wB[2][4];
    float boA[2], boB[2];
    int tt = bid;
    LOADT(wA, boA, tt);

    if (t256 == 0) {
        while (__hip_atomic_load(cnt, __ATOMIC_ACQUIRE, __HIP_MEMORY_SCOPE_AGENT) < NBLK)
            __builtin_amdgcn_s_sleep(16);
    }
    __syncthreads();
    __builtin_amdgcn_fence(__ATOMIC_ACQUIRE, "agent");

    // ---------------- phase 2: logits pipeline (R11) ----------------
    float4 hreg[4];
#pragma unroll
    for (int it = 0; it < 4; ++it)
        hreg[it] = ((const float4*)hnew)[it * 64 + lane];

    float m = -INFINITY, s = 0.f;

    for (;;) {
        const int tn = tt + NBLK;
        const bool vn = tn < NTILES;
        if (vn) LOADT(wB, boB, tn);
        COMPUTET(wA, boA, tt);
        if (!vn) break;
        const int tn2 = tn + NBLK;
        const bool vn2 = tn2 < NTILES;
        if (vn2) LOADT(wA, boA, tn2);
        COMPUTET(wB, boB, tn);
        if (!vn2) break;
        tt = tn2;
    }

    if (lane == 0) { wm[wave] = m; wsv[wave] = s; }
    __syncthreads();
    if (t256 == 0) {
        float M = wm[0], S = wsv[0];
#pragma unroll
        for (int w2 = 1; w2 < 4; ++w2) sm_merge(M, S, wm[w2], wsv[w2]);
        pmax[bid] = M;
        psum[bid] = S;
    }
}

// finalize: every block merges all NBLK partials in identical order
// (bit-identical total), then float4 in-place subtract over d_out[0..V).
__global__ __launch_bounds__(256) void finalize_kernel(
    const float* __restrict__ pmax, const float* __restrict__ psum,
    float* __restrict__ out)
{
    __shared__ float wm[4], wsv[4];
    __shared__ float total_s;
    const int tid = threadIdx.x;

    float m = -INFINITY, s = 0.f;
    for (int i = tid; i < NBLK; i += 256)
        sm_merge(m, s, pmax[i], psum[i]);
#pragma unroll
    for (int off = 32; off >= 1; off >>= 1) {
        const float mo = __shfl_xor(m, off, 64);
        const float so = __shfl_xor(s, off, 64);
        sm_merge(m, s, mo, so);
    }
    if ((tid & 63) == 0) { wm[tid >> 6] = m; wsv[tid >> 6] = s; }
    __syncthreads();
    if (tid == 0) {
        float M = wm[0], S = wsv[0];
#pragma unroll
        for (int w2 = 1; w2 < 4; ++w2) sm_merge(M, S, wm[w2], wsv[w2]);
        total_s = M + logf(S);
    }
    __syncthreads();
    const float t = total_s;

    float4* out4 = (float4*)out;
    const int n4 = V / 4;                    // 12564 -> covers 0..50255
    for (int i = blockIdx.x * 256 + tid; i < n4; i += NB_FINAL * 256) {
        float4 v = out4[i];
        v.x -= t; v.y -= t; v.z -= t; v.w -= t;
        out4[i] = v;
    }
    if (blockIdx.x == 0 && tid == 0) out[V - 1] -= t;   // 50256
}

extern "C" void kernel_launch(void* const* d_in, const int* in_sizes, int n_in,
                              void* d_out, int out_size, void* d_ws, size_t ws_size,
                              hipStream_t stream) {
    const int*   ids    = (const int*)  d_in[0];
    const float* hidden = (const float*)d_in[1];
    const float* emb    = (const float*)d_in[2];
    const float* W_ih   = (const float*)d_in[3];
    const float* W_hh   = (const float*)d_in[4];
    const float* b_ih   = (const float*)d_in[5];
    const float* b_hh   = (const float*)d_in[6];
    const float* W_out  = (const float*)d_in[7];
    const float* b_out  = (const float*)d_in[8];

    float* out = (float*)d_out;        // [0..V) logp, [V..V+H) hidden_out

    float* ws   = (float*)d_ws;
    float* hnew = ws;                          // H
    float* pmax = ws + H;                      // NBLK
    float* psum = pmax + NBLK;                 // NBLK
    unsigned int* cnt = (unsigned int*)(psum + NBLK);  // 1

    // reset the barrier counter every call (graph replays do not re-poison ws)
    (void)hipMemsetAsync((void*)cnt, 0, sizeof(unsigned int), stream);

    decoder_main_kernel<<<NBLK, 256, 0, stream>>>(
        ids, emb, hidden, W_ih, W_hh, b_ih, b_hh, W_out, b_out,
        out, out + V, hnew, pmax, psum, cnt);
    finalize_kernel<<<NB_FINAL, 256, 0, stream>>>(pmax, psum, out);
}

// Round 14
// 52.229 us; speedup vs baseline: 2.3611x; 2.3611x over previous
//
#include <hip/hip_runtime.h>
#include <math.h>

#define H 1024
#define V 50257
#define NBLK 512         // logits blocks; block b owns 98+(b<81) contiguous rows
#define ROWS_BASE 98     // 512*98 = 50176; remainder 81
#define REM 81
#define STEPS 13         // ceil(99/8); uniform for all blocks
#define NB_FINAL 64

typedef float f32x4 __attribute__((ext_vector_type(4)));

// nontemporal float4 load: weight streams are single-use, >> L2
__device__ __forceinline__ float4 ntload4(const float* p) {
    f32x4 v = __builtin_nontemporal_load((const f32x4*)p);
    return make_float4(v.x, v.y, v.z, v.w);
}

__device__ __forceinline__ float wave_reduce_sum(float v) {
#pragma unroll
    for (int off = 32; off >= 1; off >>= 1)
        v += __shfl_xor(v, off, 64);
    return v;
}

// online softmax merge: (m,s) <- merge((m,s),(mi,si))
__device__ __forceinline__ void sm_merge(float& m, float& s, float mi, float si) {
    if (mi > m) {
        s = s * expf(m - mi) + si;   // m==-inf, s==0 -> si
        m = mi;
    } else if (si > 0.f) {
        s += si * expf(mi - m);
    }
}

// K1: fused gates + GRU combine. One block per hidden index j (R9/R11 proven).
__global__ __launch_bounds__(256) void gru_fused_kernel(
    const int* __restrict__ ids, const float* __restrict__ emb,
    const float* __restrict__ hidden,
    const float* __restrict__ W_ih, const float* __restrict__ W_hh,
    const float* __restrict__ b_ih, const float* __restrict__ b_hh,
    float* __restrict__ hnew, float* __restrict__ out_hidden)
{
    const int j = blockIdx.x;
    const int t = threadIdx.x;
    const int wave = t >> 6;
    const int lane = t & 63;

    const int id = ids[0];

    float4 x4 = ((const float4*)(emb + (size_t)id * H))[t];
    const float4 h4 = ((const float4*)hidden)[t];
    float4 wi[3], wh[3];
#pragma unroll
    for (int g = 0; g < 3; ++g) {
        wi[g] = ntload4(W_ih + ((size_t)g * H + j) * H + 4 * t);
        wh[g] = ntload4(W_hh + ((size_t)g * H + j) * H + 4 * t);
    }

    x4.x = fmaxf(x4.x, 0.f); x4.y = fmaxf(x4.y, 0.f);
    x4.z = fmaxf(x4.z, 0.f); x4.w = fmaxf(x4.w, 0.f);

    float acc[6];
#pragma unroll
    for (int g = 0; g < 3; ++g) {
        acc[2*g]   = wi[g].x * x4.x + wi[g].y * x4.y + wi[g].z * x4.z + wi[g].w * x4.w;
        acc[2*g+1] = wh[g].x * h4.x + wh[g].y * h4.y + wh[g].z * h4.z + wh[g].w * h4.w;
    }
#pragma unroll
    for (int g = 0; g < 6; ++g) acc[g] = wave_reduce_sum(acc[g]);

    __shared__ float red[4][6];
    if (lane == 0) {
#pragma unroll
        for (int g = 0; g < 6; ++g) red[wave][g] = acc[g];
    }
    __syncthreads();
    if (t == 0) {
        float tt[6];
#pragma unroll
        for (int g = 0; g < 6; ++g)
            tt[g] = red[0][g] + red[1][g] + red[2][g] + red[3][g];
        const float ir  = tt[0] + b_ih[j],        hr_ = tt[1] + b_hh[j];
        const float iz  = tt[2] + b_ih[H + j],    hz  = tt[3] + b_hh[H + j];
        const float in_ = tt[4] + b_ih[2*H + j],  hn  = tt[5] + b_hh[2*H + j];
        const float r = 1.f / (1.f + expf(-(ir + hr_)));
        const float z = 1.f / (1.f + expf(-(iz + hz)));
        const float n = tanhf(in_ + r * hn);
        const float h = hidden[j];
        const float o = (1.f - z) * n + z * h;
        hnew[j] = o;
        out_hidden[j] = o;
    }
}

// K2: persistent logits + per-block softmax partials, balanced contiguous
// spans. Block b owns rows [row_start, row_end): 98+(b<81) rows; ALL blocks
// run exactly STEPS=13 double-buffered steps (8 rows/step, 2 rows/wave) --
// no tail round of idle blocks (R11 had 139/512 blocks doing a 13th tile).
// Wave-uniform guards skip invalid rows (no redundant clamped fetches).

#define LOADT(W, BO, step) do {                                               \
    const int _r0 = row_start + (step) * 8 + wave * 2;                        \
    _Pragma("unroll")                                                         \
    for (int _r = 0; _r < 2; ++_r) {                                          \
        const int _row = _r0 + _r;                                            \
        if (_row < row_end) {                                                 \
            const float* _w = W_out + (size_t)_row * H;                       \
            _Pragma("unroll")                                                 \
            for (int _it = 0; _it < 4; ++_it)                                 \
                W[_r][_it] = ntload4(_w + (_it * 64 + lane) * 4);             \
            BO[_r] = b_out[_row];                                             \
        }                                                                     \
    }                                                                         \
} while (0)

#define COMPUTET(W, BO, step) do {                                            \
    const int _r0 = row_start + (step) * 8 + wave * 2;                        \
    _Pragma("unroll")                                                         \
    for (int _r = 0; _r < 2; ++_r) {                                          \
        const int _row = _r0 + _r;                                            \
        if (_row < row_end) {                                                 \
            float _acc =                                                      \
                  W[_r][0].x * hreg[0].x + W[_r][0].y * hreg[0].y             \
                + W[_r][0].z * hreg[0].z + W[_r][0].w * hreg[0].w             \
                + W[_r][1].x * hreg[1].x + W[_r][1].y * hreg[1].y             \
                + W[_r][1].z * hreg[1].z + W[_r][1].w * hreg[1].w             \
                + W[_r][2].x * hreg[2].x + W[_r][2].y * hreg[2].y             \
                + W[_r][2].z * hreg[2].z + W[_r][2].w * hreg[2].w             \
                + W[_r][3].x * hreg[3].x + W[_r][3].y * hreg[3].y             \
                + W[_r][3].z * hreg[3].z + W[_r][3].w * hreg[3].w;            \
            _acc = wave_reduce_sum(_acc);                                     \
            if (lane == 0) {                                                  \
                const float _lg = _acc + BO[_r];                              \
                logits[_row] = _lg;                                           \
                sm_merge(m, s, _lg, 1.f);                                     \
            }                                                                 \
        }                                                                     \
    }                                                                         \
} while (0)

__global__ __launch_bounds__(256, 4) void logits_persistent_kernel(
    const float* __restrict__ hnew, const float* __restrict__ W_out,
    const float* __restrict__ b_out, float* __restrict__ logits,
    float* __restrict__ pmax, float* __restrict__ psum)
{
    __shared__ float wm[4], wsv[4];
    const int wave = threadIdx.x >> 6;
    const int lane = threadIdx.x & 63;
    const int bid  = blockIdx.x;

    const int row_start = bid * ROWS_BASE + (bid < REM ? bid : REM);
    const int row_end   = row_start + ROWS_BASE + (bid < REM ? 1 : 0);

    float4 hreg[4];
#pragma unroll
    for (int it = 0; it < 4; ++it)
        hreg[it] = ((const float4*)hnew)[it * 64 + lane];

    float m = -INFINITY, s = 0.f;

    float4 wA[2][4], wB[2][4];
    float boA[2], boB[2];
    int st = 0;
    LOADT(wA, boA, 0);
    for (;;) {
        if (st + 1 < STEPS) LOADT(wB, boB, st + 1);
        COMPUTET(wA, boA, st);
        if (st + 1 >= STEPS) break;
        if (st + 2 < STEPS) LOADT(wA, boA, st + 2);
        COMPUTET(wB, boB, st + 1);
        if (st + 2 >= STEPS) break;
        st += 2;
    }

    if (lane == 0) { wm[wave] = m; wsv[wave] = s; }
    __syncthreads();
    if (threadIdx.x == 0) {
        float M = wm[0], S = wsv[0];
#pragma unroll
        for (int w2 = 1; w2 < 4; ++w2) sm_merge(M, S, wm[w2], wsv[w2]);
        pmax[bid] = M;
        psum[bid] = S;
    }
}

// K3: fused final reduce + logp (float4 subtract). Every block merges all
// NBLK partials in identical order -> bit-identical total.
__global__ __launch_bounds__(256) void finalize_kernel(
    const float* __restrict__ pmax, const float* __restrict__ psum,
    float* __restrict__ out)
{
    __shared__ float wm[4], wsv[4];
    __shared__ float total_s;
    const int tid = threadIdx.x;

    float m = -INFINITY, s = 0.f;
    for (int i = tid; i < NBLK; i += 256)
        sm_merge(m, s, pmax[i], psum[i]);
#pragma unroll
    for (int off = 32; off >= 1; off >>= 1) {
        const float mo = __shfl_xor(m, off, 64);
        const float so = __shfl_xor(s, off, 64);
        sm_merge(m, s, mo, so);
    }
    if ((tid & 63) == 0) { wm[tid >> 6] = m; wsv[tid >> 6] = s; }
    __syncthreads();
    if (tid == 0) {
        float M = wm[0], S = wsv[0];
#pragma unroll
        for (int w2 = 1; w2 < 4; ++w2) sm_merge(M, S, wm[w2], wsv[w2]);
        total_s = M + logf(S);
    }
    __syncthreads();
    const float t = total_s;

    float4* out4 = (float4*)out;
    const int n4 = V / 4;                    // 12564 -> covers 0..50255
    for (int i = blockIdx.x * 256 + tid; i < n4; i += NB_FINAL * 256) {
        float4 v = out4[i];
        v.x -= t; v.y -= t; v.z -= t; v.w -= t;
        out4[i] = v;
    }
    if (blockIdx.x == 0 && tid == 0) out[V - 1] -= t;   // 50256
}

extern "C" void kernel_launch(void* const* d_in, const int* in_sizes, int n_in,
                              void* d_out, int out_size, void* d_ws, size_t ws_size,
                              hipStream_t stream) {
    const int*   ids    = (const int*)  d_in[0];
    const float* hidden = (const float*)d_in[1];
    const float* emb    = (const float*)d_in[2];
    const float* W_ih   = (const float*)d_in[3];
    const float* W_hh   = (const float*)d_in[4];
    const float* b_ih   = (const float*)d_in[5];
    const float* b_hh   = (const float*)d_in[6];
    const float* W_out  = (const float*)d_in[7];
    const float* b_out  = (const float*)d_in[8];

    float* out = (float*)d_out;        // [0..V) logp, [V..V+H) hidden_out

    float* ws   = (float*)d_ws;
    float* hnew = ws;                  // H
    float* pmax = ws + H;              // NBLK
    float* psum = pmax + NBLK;         // NBLK

    gru_fused_kernel<<<H, 256, 0, stream>>>(ids, emb, hidden, W_ih, W_hh,
                                            b_ih, b_hh, hnew, out + V);
    logits_persistent_kernel<<<NBLK, 256, 0, stream>>>(hnew, W_out, b_out, out,
                                                       pmax, psum);
    finalize_kernel<<<NB_FINAL, 256, 0, stream>>>(pmax, psum, out);
}

// Round 15
// 46.067 us; speedup vs baseline: 2.6770x; 1.1338x over previous
//
#include <hip/hip_runtime.h>
#include <math.h>

#define H 1024
#define V 50257
#define NTILES 6283      // ceil(V / 8) tiles of 8 rows (2 rows per wave)
#define NBLK 512         // persistent logits blocks
#define NB_FINAL 64

typedef float f32x4 __attribute__((ext_vector_type(4)));

// nontemporal float4 load: W streams are single-use, 50x larger than L2 --
// bypass/deprioritize cache allocation to avoid L2 thrash on the stream.
__device__ __forceinline__ float4 ntload4(const float* p) {
    f32x4 v = __builtin_nontemporal_load((const f32x4*)p);
    return make_float4(v.x, v.y, v.z, v.w);
}

__device__ __forceinline__ float wave_reduce_sum(float v) {
#pragma unroll
    for (int off = 32; off >= 1; off >>= 1)
        v += __shfl_xor(v, off, 64);
    return v;
}

// online softmax merge: (m,s) <- merge((m,s),(mi,si))
__device__ __forceinline__ void sm_merge(float& m, float& s, float mi, float si) {
    if (mi > m) {
        s = s * expf(m - mi) + si;   // m==-inf, s==0 -> si
        m = mi;
    } else if (si > 0.f) {
        s += si * expf(mi - m);
    }
}

// K1: fused gates + GRU combine. One block per hidden index j (R9 structure).
__global__ __launch_bounds__(256) void gru_fused_kernel(
    const int* __restrict__ ids, const float* __restrict__ emb,
    const float* __restrict__ hidden,
    const float* __restrict__ W_ih, const float* __restrict__ W_hh,
    const float* __restrict__ b_ih, const float* __restrict__ b_hh,
    float* __restrict__ hnew, float* __restrict__ out_hidden)
{
    const int j = blockIdx.x;
    const int t = threadIdx.x;
    const int wave = t >> 6;
    const int lane = t & 63;

    const int id = ids[0];

    float4 x4 = ((const float4*)(emb + (size_t)id * H))[t];
    const float4 h4 = ((const float4*)hidden)[t];
    float4 wi[3], wh[3];
#pragma unroll
    for (int g = 0; g < 3; ++g) {
        wi[g] = ntload4(W_ih + ((size_t)g * H + j) * H + 4 * t);
        wh[g] = ntload4(W_hh + ((size_t)g * H + j) * H + 4 * t);
    }

    x4.x = fmaxf(x4.x, 0.f); x4.y = fmaxf(x4.y, 0.f);
    x4.z = fmaxf(x4.z, 0.f); x4.w = fmaxf(x4.w, 0.f);

    float acc[6];
#pragma unroll
    for (int g = 0; g < 3; ++g) {
        acc[2*g]   = wi[g].x * x4.x + wi[g].y * x4.y + wi[g].z * x4.z + wi[g].w * x4.w;
        acc[2*g+1] = wh[g].x * h4.x + wh[g].y * h4.y + wh[g].z * h4.z + wh[g].w * h4.w;
    }
#pragma unroll
    for (int g = 0; g < 6; ++g) acc[g] = wave_reduce_sum(acc[g]);

    __shared__ float red[4][6];
    if (lane == 0) {
#pragma unroll
        for (int g = 0; g < 6; ++g) red[wave][g] = acc[g];
    }
    __syncthreads();
    if (t == 0) {
        float tt[6];
#pragma unroll
        for (int g = 0; g < 6; ++g)
            tt[g] = red[0][g] + red[1][g] + red[2][g] + red[3][g];
        const float ir  = tt[0] + b_ih[j],        hr_ = tt[1] + b_hh[j];
        const float iz  = tt[2] + b_ih[H + j],    hz  = tt[3] + b_hh[H + j];
        const float in_ = tt[4] + b_ih[2*H + j],  hn  = tt[5] + b_hh[2*H + j];
        const float r = 1.f / (1.f + expf(-(ir + hr_)));
        const float z = 1.f / (1.f + expf(-(iz + hz)));
        const float n = tanhf(in_ + r * hn);
        const float h = hidden[j];
        const float o = (1.f - z) * n + z * h;
        hnew[j] = o;
        out_hidden[j] = o;
    }
}

// K2: persistent, software-pipelined logits + per-block softmax partials.
// 512 blocks; tiles of 8 rows (2 rows/wave). Double-buffered register
// prefetch of weights AND b_out; nontemporal W_out loads (single-use stream).
// 16 waves/CU via __launch_bounds__(256,4). ~6.1 TB/s = 97% of the measured
// read ceiling (m13: 6.29 TB/s). Clamped redundant tail loads, NOT per-row
// guards: R14 proved guards break the unconditional load batch (-5us).

#define LOADT(W, BO, tile) do {                                               \
    const int _b = (tile) * 8 + wave * 2;                                     \
    _Pragma("unroll")                                                         \
    for (int _r = 0; _r < 2; ++_r) {                                          \
        const int _row = (_b + _r < V) ? (_b + _r) : (V - 1);                 \
        const float* _w = W_out + (size_t)_row * H;                           \
        _Pragma("unroll")                                                     \
        for (int _it = 0; _it < 4; ++_it)                                     \
            W[_r][_it] = ntload4(_w + (_it * 64 + lane) * 4);                 \
        BO[_r] = b_out[_row];                                                 \
    }                                                                         \
} while (0)

#define COMPUTET(W, BO, tile) do {                                            \
    const int _b = (tile) * 8 + wave * 2;                                     \
    float _acc[2];                                                            \
    _Pragma("unroll")                                                         \
    for (int _r = 0; _r < 2; ++_r) {                                          \
        _acc[_r] = W[_r][0].x * hreg[0].x + W[_r][0].y * hreg[0].y            \
                 + W[_r][0].z * hreg[0].z + W[_r][0].w * hreg[0].w            \
                 + W[_r][1].x * hreg[1].x + W[_r][1].y * hreg[1].y            \
                 + W[_r][1].z * hreg[1].z + W[_r][1].w * hreg[1].w            \
                 + W[_r][2].x * hreg[2].x + W[_r][2].y * hreg[2].y            \
                 + W[_r][2].z * hreg[2].z + W[_r][2].w * hreg[2].w            \
                 + W[_r][3].x * hreg[3].x + W[_r][3].y * hreg[3].y            \
                 + W[_r][3].z * hreg[3].z + W[_r][3].w * hreg[3].w;           \
    }                                                                         \
    _Pragma("unroll")                                                         \
    for (int _r = 0; _r < 2; ++_r) _acc[_r] = wave_reduce_sum(_acc[_r]);      \
    if (lane == 0) {                                                          \
        _Pragma("unroll")                                                     \
        for (int _r = 0; _r < 2; ++_r) {                                      \
            const int _row = _b + _r;                                         \
            if (_row < V) {                                                   \
                const float _lg = _acc[_r] + BO[_r];                          \
                logits[_row] = _lg;                                           \
                sm_merge(m, s, _lg, 1.f);                                     \
            }                                                                 \
        }                                                                     \
    }                                                                         \
} while (0)

__global__ __launch_bounds__(256, 4) void logits_persistent_kernel(
    const float* __restrict__ hnew, const float* __restrict__ W_out,
    const float* __restrict__ b_out, float* __restrict__ logits,
    float* __restrict__ pmax, float* __restrict__ psum)
{
    __shared__ float wm[4], wsv[4];
    const int wave = threadIdx.x >> 6;
    const int lane = threadIdx.x & 63;
    const int bid  = blockIdx.x;

    float4 hreg[4];
#pragma unroll
    for (int it = 0; it < 4; ++it)
        hreg[it] = ((const float4*)hnew)[it * 64 + lane];

    float m = -INFINITY, s = 0.f;

    float4 wA[2][4], wB[2][4];
    float boA[2], boB[2];
    int t = bid;                         // every block has >= 12 tiles
    LOADT(wA, boA, t);
    for (;;) {
        const int tn = t + NBLK;
        const bool vn = tn < NTILES;
        if (vn) LOADT(wB, boB, tn);
        COMPUTET(wA, boA, t);
        if (!vn) break;
        const int tn2 = tn + NBLK;
        const bool vn2 = tn2 < NTILES;
        if (vn2) LOADT(wA, boA, tn2);
        COMPUTET(wB, boB, tn);
        if (!vn2) break;
        t = tn2;
    }

    if (lane == 0) { wm[wave] = m; wsv[wave] = s; }
    __syncthreads();
    if (threadIdx.x == 0) {
        float M = wm[0], S = wsv[0];
#pragma unroll
        for (int w2 = 1; w2 < 4; ++w2) sm_merge(M, S, wm[w2], wsv[w2]);
        pmax[bid] = M;
        psum[bid] = S;
    }
}

// K3: fused final reduce + logp (float4 subtract). Every block merges all
// NBLK partials in identical order -> bit-identical total.
__global__ __launch_bounds__(256) void finalize_kernel(
    const float* __restrict__ pmax, const float* __restrict__ psum,
    float* __restrict__ out)
{
    __shared__ float wm[4], wsv[4];
    __shared__ float total_s;
    const int tid = threadIdx.x;

    float m = -INFINITY, s = 0.f;
    for (int i = tid; i < NBLK; i += 256)
        sm_merge(m, s, pmax[i], psum[i]);
#pragma unroll
    for (int off = 32; off >= 1; off >>= 1) {
        const float mo = __shfl_xor(m, off, 64);
        const float so = __shfl_xor(s, off, 64);
        sm_merge(m, s, mo, so);
    }
    if ((tid & 63) == 0) { wm[tid >> 6] = m; wsv[tid >> 6] = s; }
    __syncthreads();
    if (tid == 0) {
        float M = wm[0], S = wsv[0];
#pragma unroll
        for (int w2 = 1; w2 < 4; ++w2) sm_merge(M, S, wm[w2], wsv[w2]);
        total_s = M + logf(S);
    }
    __syncthreads();
    const float t = total_s;

    float4* out4 = (float4*)out;
    const int n4 = V / 4;                    // 12564 -> covers 0..50255
    for (int i = blockIdx.x * 256 + tid; i < n4; i += NB_FINAL * 256) {
        float4 v = out4[i];
        v.x -= t; v.y -= t; v.z -= t; v.w -= t;
        out4[i] = v;
    }
    if (blockIdx.x == 0 && tid == 0) out[V - 1] -= t;   // 50256
}

extern "C" void kernel_launch(void* const* d_in, const int* in_sizes, int n_in,
                              void* d_out, int out_size, void* d_ws, size_t ws_size,
                              hipStream_t stream) {
    const int*   ids    = (const int*)  d_in[0];
    const float* hidden = (const float*)d_in[1];
    const float* emb    = (const float*)d_in[2];
    const float* W_ih   = (const float*)d_in[3];
    const float* W_hh   = (const float*)d_in[4];
    const float* b_ih   = (const float*)d_in[5];
    const float* b_hh   = (const float*)d_in[6];
    const float* W_out  = (const float*)d_in[7];
    const float* b_out  = (const float*)d_in[8];

    float* out = (float*)d_out;        // [0..V) logp, [V..V+H) hidden_out

    float* ws   = (float*)d_ws;
    float* hnew = ws;                  // H
    float* pmax = ws + H;              // NBLK
    float* psum = pmax + NBLK;         // NBLK

    gru_fused_kernel<<<H, 256, 0, stream>>>(ids, emb, hidden, W_ih, W_hh,
                                            b_ih, b_hh, hnew, out + V);
    logits_persistent_kernel<<<NBLK, 256, 0, stream>>>(hnew, W_out, b_out, out,
                                                       pmax, psum);
    finalize_kernel<<<NB_FINAL, 256, 0, stream>>>(pmax, psum, out);
}